// Round 10
// baseline (219.849 us; speedup 1.0000x reference)
//
#include <hip/hip_runtime.h>

// Problem constants (from reference)
#define B 1024
#define R 256
#define D 512
#define G 4

#define LOG2E 1.44269504088896340736f

// Workspace layout (float offsets). Total = 2,886,656 floats = 11.55 MB.
// PB: per (r, chunk-of-2-d): [fb(2) | fa(2) | q0(2) | q1(2) | q2(2) | q3(2)] = 12 floats (48 B)
//   t = fa*x + fb ; exp2(t) = exp(-kappa*ineq*(x-th)) ; sigmoid = 1/(1+exp2(t))
//   qg = sigmoid(ml)*tanh(esp)*softmax(A)_g
#define OFF_PB   0                       // [R][256][12]
#define OFF_EPI  (R*256*12)              // [R][12]  {offe0..3, gm0..3, k8e, hw, pad, pad}
#define OFF_PART (OFF_EPI + R*12)        // [R][2 dh][B][4 g] raw acc partials
#define NBT 16                           // b-tiles (64 b per block)

typedef float f2 __attribute__((ext_vector_type(2)));
static __device__ __forceinline__ f2 mk2(float a, float b) { f2 v; v.x = a; v.y = b; return v; }

__device__ __forceinline__ float rcp_f(float v)  { return __builtin_amdgcn_rcpf(v); }
__device__ __forceinline__ float exp2_f(float v) { return __builtin_amdgcn_exp2f(v); }
__device__ __forceinline__ float sig_f(float v)  { return rcp_f(1.0f + exp2_f(-v * LOG2E)); }
__device__ __forceinline__ float tanh_f(float v) {
    const float q2 = exp2_f(v * (2.0f * LOG2E));
    return (q2 - 1.0f) * rcp_f(q2 + 1.0f);
}

// ---------------- Kernel 1: fold all b-independent math ----------------
__global__ __launch_bounds__(256)
void sge_precompute(const float* __restrict__ th,  const float* __restrict__ isp,
                    const float* __restrict__ esp, const float* __restrict__ ml,
                    const float* __restrict__ lk,  const float* __restrict__ gl,
                    const float* __restrict__ tg,  const float* __restrict__ gml,
                    const float* __restrict__ kf,  const float* __restrict__ hw,
                    float* __restrict__ ws)
{
    const int r   = blockIdx.x;
    const int tid = threadIdx.x;
    __shared__ float4 red[256];

    float kappa = exp2_f(lk[0] * LOG2E);
    kappa = fminf(fmaxf(kappa, 0.5f), 50.0f);

    float4 psum = make_float4(0.f, 0.f, 0.f, 0.f);
    for (int d = tid; d < D; d += 256) {
        const int idx = r * D + d;
        const float thv  = th[idx];
        const float ineq = tanh_f(isp[idx]);
        const float es   = tanh_f(esp[idx]);
        const float mm   = sig_f(ml[idx]);
        // softmax over g (axis 0) of group_logits[:, d]
        const float g0 = gl[0*D + d], g1 = gl[1*D + d], g2 = gl[2*D + d], g3 = gl[3*D + d];
        const float mx = fmaxf(fmaxf(g0, g1), fmaxf(g2, g3));
        const float e0 = exp2_f((g0 - mx) * LOG2E), e1 = exp2_f((g1 - mx) * LOG2E);
        const float e2 = exp2_f((g2 - mx) * LOG2E), e3 = exp2_f((g3 - mx) * LOG2E);
        const float inv = 1.0f / (e0 + e1 + e2 + e3);
        const float a0 = e0 * inv, a1 = e1 * inv, a2 = e2 * inv, a3 = e3 * inv;

        const float fa = -kappa * ineq * LOG2E;   // exp2(fa*x+fb) == exp(-kappa*ineq*(x-th))
        const float fb = -fa * thv;
        const float s  = mm * es;
        const float s0 = s * a0, s1 = s * a1, s2 = s * a2, s3 = s * a3;

        const int chunk = d >> 1, j = d & 1;
        float* pc = ws + OFF_PB + ((size_t)r * 256 + chunk) * 12;
        pc[j]      = fb;
        pc[2 + j]  = fa;
        pc[4 + j]  = s0;
        pc[6 + j]  = s1;
        pc[8 + j]  = s2;
        pc[10 + j] = s3;
        psum.x += s0; psum.y += s1; psum.z += s2; psum.w += s3;
    }
    red[tid] = psum;
    __syncthreads();
    for (int s = 128; s > 0; s >>= 1) {
        if (tid < s) {
            red[tid].x += red[tid + s].x;
            red[tid].y += red[tid + s].y;
            red[tid].z += red[tid + s].z;
            red[tid].w += red[tid + s].w;
        }
        __syncthreads();
    }
    if (tid == 0) {
        const float4 base = red[0];
        const float gm0 = sig_f(gml[r * G + 0]);
        const float gm1 = sig_f(gml[r * G + 1]);
        const float gm2 = sig_f(gml[r * G + 2]);
        const float gm3 = sig_f(gml[r * G + 3]);
        const float en  = gm0 + gm1 + gm2 + gm3 + 1e-6f;
        const float k   = sig_f(kf[r]) * en;
        float* epi = ws + OFF_EPI + r * 12;
        // pg_g = sigmoid(12*acc_g - 6*(base_g+tg_g))  ->  exp2 arg = fma(C12, acc, offe)
        epi[0] = 6.0f * (base.x + tg[r * G + 0]) * LOG2E;
        epi[1] = 6.0f * (base.y + tg[r * G + 1]) * LOG2E;
        epi[2] = 6.0f * (base.z + tg[r * G + 2]) * LOG2E;
        epi[3] = 6.0f * (base.w + tg[r * G + 3]) * LOG2E;
        epi[4] = gm0; epi[5] = gm1; epi[6] = gm2; epi[7] = gm3;
        epi[8] = 8.0f * k * LOG2E;   // z = sigmoid(8*score - 8k) -> exp2 arg = fma(C8, score, k8e)
        epi[9] = hw[r];
        epi[10] = 0.f; epi[11] = 0.f;
    }
}

// ---------------- Kernel 2: the 134M-element hot loop ----------------
// Grid: 16 b-tiles x (16 r-blocks x 2 d-halves) = 512 blocks (2/CU by design).
// Block: 512 thr = 8 waves; wave w owns the r-pair (r0 = rblk*16+2w, r1 = r0+1)
// over 64 b (lane = b) x 256 d. x staged ONCE in LDS (pitch 258), read as
// ds_read_b64 per 2-d chunk and shared by both r's. Params arrive via VMEM
// BROADCAST loads (all lanes same address -> 1 transaction): VMEM is IN-ORDER,
// so the compiler emits precise vmcnt(N) waits and the 3-slot/6-phase rotation
// (reload distance 3 phases ~360 cyc) genuinely pipelines -- unlike s_load,
// whose out-of-order completion forces lgkmcnt(0) drains (the ~55% VALUBusy
// cap of R3/R6/R7). x (lgkm) and params (vmcnt) are on separate counters.
//
// R9 LESSON: __launch_bounds__(512,4) only sets the MINIMUM waves/EU; the
// backend's occupancy heuristic still targeted 8 waves/EU (64-VGPR cap) and
// spilled the ~110-reg live set to scratch (VGPR_Count=64, WRITE_SIZE=76MB,
// 211us). amdgpu_waves_per_eu(4,4) pins min=max=4 -> VGPR cap 128, no
// spill-for-occupancy.
struct PB4 { float4 a, b, c; };   // one r's one-chunk params: {fb2|fa2 , q0|q1 , q2|q3}

__global__ __launch_bounds__(512)
__attribute__((amdgpu_waves_per_eu(4, 4)))
void sge_main(const float* __restrict__ x, const float* __restrict__ ws,
              float* __restrict__ part)
{
    __shared__ float xl[64 * 258];   // 66 KB: 64 b rows x 256 d, pitch 258

    const int tid  = threadIdx.x;
    const int lane = tid & 63;
    const int w    = __builtin_amdgcn_readfirstlane(tid >> 6);  // force wave-uniform
    const int bt   = blockIdx.x;          // 0..15
    const int rbdh = blockIdx.y;          // 0..31
    const int rblk = rbdh >> 1;           // 0..15
    const int dh   = rbdh & 1;            // d-half 0..1
    const int r0   = rblk * 16 + 2 * w;
    const int r1   = r0 + 1;

    // ---- stage x: 64 b x 256 d (this d-half) = 64x64 float4 = 4096 quads,
    //      8 iterations of 512 threads ----
    #pragma unroll
    for (int k = 0; k < 8; ++k) {
        const int i   = tid + k * 512;
        const int row = i >> 6, c4 = i & 63;
        const float4 v = reinterpret_cast<const float4*>(x)[(size_t)(bt * 64 + row) * 128 + dh * 64 + c4];
        f2* dst = reinterpret_cast<f2*>(&xl[row * 258 + c4 * 4]);
        dst[0] = mk2(v.x, v.y);
        dst[1] = mk2(v.z, v.w);
    }
    __syncthreads();

    // opaque zero in a VGPR: keeps param loads on the vector-memory (vmcnt) path,
    // not s_load (whose out-of-order completion would force full lgkm drains).
    int vz; asm volatile("v_mov_b32 %0, 0" : "=v"(vz));
    const float* pb0 = ws + OFF_PB + ((size_t)r0 * 256 + (size_t)dh * 128) * 12 + vz;
    const float* pb1 = ws + OFF_PB + ((size_t)r1 * 256 + (size_t)dh * 128) * 12 + vz;

    f2 a00 = mk2(0.f,0.f), a01 = mk2(0.f,0.f), a02 = mk2(0.f,0.f), a03 = mk2(0.f,0.f);
    f2 a10 = mk2(0.f,0.f), a11 = mk2(0.f,0.f), a12 = mk2(0.f,0.f), a13 = mk2(0.f,0.f);

    auto ldP = [&](PB4& p0, PB4& p1, int ch) {
        ch = (ch < 127) ? ch : 127;               // tail prefetch clamp (dead but harmless)
        const float4* q0 = reinterpret_cast<const float4*>(pb0 + (size_t)ch * 12);
        const float4* q1 = reinterpret_cast<const float4*>(pb1 + (size_t)ch * 12);
        p0.a = q0[0]; p0.b = q0[1]; p0.c = q0[2];
        p1.a = q1[0]; p1.b = q1[1]; p1.c = q1[2];
    };
    auto ldX = [&](f2& xv, int ch) {
        xv = *reinterpret_cast<const f2*>(&xl[lane * 258 + ch * 2]);
    };
    auto compute = [&](const PB4& p0, const PB4& p1, f2 xv) {
        const f2 t0 = __builtin_elementwise_fma(xv, mk2(p0.a.z, p0.a.w), mk2(p0.a.x, p0.a.y));
        const f2 t1 = __builtin_elementwise_fma(xv, mk2(p1.a.z, p1.a.w), mk2(p1.a.x, p1.a.y));
        f2 e0, e1;
        e0.x = exp2_f(t0.x); e0.y = exp2_f(t0.y);
        e1.x = exp2_f(t1.x); e1.y = exp2_f(t1.y);
        const f2 b0 = e0 + 1.0f, b1 = e1 + 1.0f;
        const float P0 = b0.x * b0.y, P1 = b1.x * b1.y;
        const float rp = rcp_f(P0 * P1);          // ONE rcp per 4 sigmoids
        const float i0 = rp * P1, i1 = rp * P0;   // 1/P0, 1/P1
        const f2 c0 = mk2(b0.y, b0.x) * i0;       // sigmoid pair for r0
        const f2 c1 = mk2(b1.y, b1.x) * i1;       // sigmoid pair for r1
        a00 = __builtin_elementwise_fma(mk2(p0.b.x, p0.b.y), c0, a00);
        a01 = __builtin_elementwise_fma(mk2(p0.b.z, p0.b.w), c0, a01);
        a02 = __builtin_elementwise_fma(mk2(p0.c.x, p0.c.y), c0, a02);
        a03 = __builtin_elementwise_fma(mk2(p0.c.z, p0.c.w), c0, a03);
        a10 = __builtin_elementwise_fma(mk2(p1.b.x, p1.b.y), c1, a10);
        a11 = __builtin_elementwise_fma(mk2(p1.b.z, p1.b.w), c1, a11);
        a12 = __builtin_elementwise_fma(mk2(p1.c.x, p1.c.y), c1, a12);
        a13 = __builtin_elementwise_fma(mk2(p1.c.z, p1.c.w), c1, a13);
    };

    PB4 A0, A1, B0, B1, C0, C1;
    f2 xa, xb;
    ldP(A0, A1, 0); ldP(B0, B1, 1); ldP(C0, C1, 2); ldX(xa, 0);

    // 6-phase body: param slots rotate A,B,C with reload-distance 3 phases
    // (~360 cyc of cover on the in-order vmcnt stream); x alternates xa/xb at
    // distance 1 (ds latency ~70 cyc, precise partial lgkm waits).
    #pragma unroll 1
    for (int c = 0; c < 126; c += 6) {
        ldX(xb, c + 1); compute(A0, A1, xa); ldP(A0, A1, c + 3);
        ldX(xa, c + 2); compute(B0, B1, xb); ldP(B0, B1, c + 4);
        ldX(xb, c + 3); compute(C0, C1, xa); ldP(C0, C1, c + 5);
        ldX(xa, c + 4); compute(A0, A1, xb); ldP(A0, A1, c + 6);
        ldX(xb, c + 5); compute(B0, B1, xa); ldP(B0, B1, c + 7);
        ldX(xa, c + 6); compute(C0, C1, xb); ldP(C0, C1, c + 8);
    }
    // tail: chunks 126 (slot A, x in xa) and 127 (slot B)
    ldX(xb, 127);
    compute(A0, A1, xa);
    compute(B0, B1, xb);

    // ---- write raw acc partials; finalize merges d-halves + nonlinear chain ----
    const float4 v0 = make_float4(a00.x + a00.y, a01.x + a01.y, a02.x + a02.y, a03.x + a03.y);
    const float4 v1 = make_float4(a10.x + a10.y, a11.x + a11.y, a12.x + a12.y, a13.x + a13.y);
    reinterpret_cast<float4*>(part)[(size_t)(r0 * 2 + dh) * B + bt * 64 + lane] = v0;
    reinterpret_cast<float4*>(part)[(size_t)(r1 * 2 + dh) * B + bt * 64 + lane] = v1;
}

// ---------------- Kernel 3: combine d-halves, nonlinear chain, reduce r ----------------
// Grid: 16 blocks (one per 64-b group) x 512 thr = 64 lanes x 8 r-slices of 32 r.
__global__ __launch_bounds__(512)
void sge_finalize(const float* __restrict__ part, const float* __restrict__ ws,
                  const float* __restrict__ hb, float* __restrict__ y)
{
    __shared__ float red[512];
    const int tid   = threadIdx.x;
    const int lane  = tid & 63;       // b within group
    const int slice = tid >> 6;       // 0..7 (r-slices of 32)
    const int bg    = blockIdx.x;     // 0..15
    const int b     = bg * 64 + lane;
    const float C12 = -12.0f * LOG2E;
    const float C8  = -8.0f  * LOG2E;

    float s = 0.f;
    for (int rr = 0; rr < 32; ++rr) {
        const int r = slice * 32 + rr;
        const float4 v0 = reinterpret_cast<const float4*>(part)[(size_t)(r * 2 + 0) * B + b];
        const float4 v1 = reinterpret_cast<const float4*>(part)[(size_t)(r * 2 + 1) * B + b];
        const float a0 = v0.x + v1.x;
        const float a1 = v0.y + v1.y;
        const float a2 = v0.z + v1.z;
        const float a3 = v0.w + v1.w;
        const float* epi = ws + OFF_EPI + r * 12;
        const float pg0 = rcp_f(1.0f + exp2_f(fmaf(C12, a0, epi[0])));
        const float pg1 = rcp_f(1.0f + exp2_f(fmaf(C12, a1, epi[1])));
        const float pg2 = rcp_f(1.0f + exp2_f(fmaf(C12, a2, epi[2])));
        const float pg3 = rcp_f(1.0f + exp2_f(fmaf(C12, a3, epi[3])));
        float score = pg0 * epi[4];
        score = fmaf(pg1, epi[5], score);
        score = fmaf(pg2, epi[6], score);
        score = fmaf(pg3, epi[7], score);
        const float z = rcp_f(1.0f + exp2_f(fmaf(C8, score, epi[8])));
        s = fmaf(epi[9], z, s);
    }
    red[tid] = s;
    __syncthreads();
    if (slice == 0) {
        float tot = hb[0];
        #pragma unroll
        for (int k = 0; k < 8; ++k) tot += red[k * 64 + lane];
        y[b] = tot;
    }
}

extern "C" void kernel_launch(void* const* d_in, const int* in_sizes, int n_in,
                              void* d_out, int out_size, void* d_ws, size_t ws_size,
                              hipStream_t stream)
{
    const float* x   = (const float*)d_in[0];
    const float* th  = (const float*)d_in[1];
    const float* isp = (const float*)d_in[2];
    const float* esp = (const float*)d_in[3];
    const float* ml  = (const float*)d_in[4];
    const float* lk  = (const float*)d_in[5];
    const float* gl  = (const float*)d_in[6];
    const float* tg  = (const float*)d_in[7];
    const float* gml = (const float*)d_in[8];
    const float* kf  = (const float*)d_in[9];
    const float* hw  = (const float*)d_in[10];
    const float* hb  = (const float*)d_in[11];
    float* ws = (float*)d_ws;
    float* y  = (float*)d_out;

    sge_precompute<<<R, 256, 0, stream>>>(th, isp, esp, ml, lk, gl, tg, gml, kf, hw, ws);
    sge_main<<<dim3(NBT, 32), 512, 0, stream>>>(x, ws, ws + OFF_PART);
    sge_finalize<<<NBT, 512, 0, stream>>>(ws + OFF_PART, ws, hb, y);
}

// Round 11
// 101.870 us; speedup vs baseline: 2.1581x; 2.1581x over previous
//
#include <hip/hip_runtime.h>

// Problem constants (from reference)
#define B 1024
#define R 256
#define D 512
#define G 4

#define LOG2E 1.44269504088896340736f

// Workspace layout (float offsets). Total = 2,370,560 floats = 9.48 MB (< R7's proven 11.55 MB).
// PB: per (r, chunk-of-2-d): [fb(2) | fa(2) | q0(2) | q1(2) | q2(2) | q3(2)] = 12 floats (48 B)
//   t = fa*x + fb ; exp2(t) = exp(-kappa*ineq*(x-th)) ; sigmoid = 1/(1+exp2(t))
//   qg = sigmoid(ml)*tanh(esp)*softmax(A)_g
#define OFF_PB   0                         // [R][256][12]
#define OFF_EPI  (R*256*12)                // [R][12]  {offe0..3, gm0..3, k8e, hw, pad, pad}
#define OFF_XT   (OFF_EPI + R*12)          // [D][B]   x transposed
#define OFF_PART (OFF_XT + D*B)            // [R][B][4] merged acc (f4 per (r,b))
#define OFF_ZP   (OFF_PART + R*B*4)        // [8][B]   per-r-slice partial of y

typedef float f2 __attribute__((ext_vector_type(2)));
static __device__ __forceinline__ f2 mk2(float a, float b) { f2 v; v.x = a; v.y = b; return v; }

__device__ __forceinline__ float rcp_f(float v)  { return __builtin_amdgcn_rcpf(v); }
__device__ __forceinline__ float exp2_f(float v) { return __builtin_amdgcn_exp2f(v); }
__device__ __forceinline__ float sig_f(float v)  { return rcp_f(1.0f + exp2_f(-v * LOG2E)); }
__device__ __forceinline__ float tanh_f(float v) {
    const float q2 = exp2_f(v * (2.0f * LOG2E));
    return (q2 - 1.0f) * rcp_f(q2 + 1.0f);
}

// ---------------- Kernel 0: transpose x -> xT[d][b] (verbatim from R5, proven) ----------------
__global__ __launch_bounds__(256)
void sge_transpose(const float* __restrict__ x, float* __restrict__ xT)
{
    __shared__ float t[64][65];
    const int tid = threadIdx.x, tx = tid & 63, ty = tid >> 6;
    const int d0 = blockIdx.x * 64, b0 = blockIdx.y * 64;
    #pragma unroll
    for (int i = 0; i < 64; i += 4)
        t[ty + i][tx] = x[(size_t)(b0 + ty + i) * D + d0 + tx];
    __syncthreads();
    #pragma unroll
    for (int i = 0; i < 64; i += 4)
        xT[(size_t)(d0 + ty + i) * B + b0 + tx] = t[tx][ty + i];
}

// ---------------- Kernel 1: fold all b-independent math (verbatim from R7) ----------------
__global__ __launch_bounds__(256)
void sge_precompute(const float* __restrict__ th,  const float* __restrict__ isp,
                    const float* __restrict__ esp, const float* __restrict__ ml,
                    const float* __restrict__ lk,  const float* __restrict__ gl,
                    const float* __restrict__ tg,  const float* __restrict__ gml,
                    const float* __restrict__ kf,  const float* __restrict__ hw,
                    float* __restrict__ ws)
{
    const int r   = blockIdx.x;
    const int tid = threadIdx.x;
    __shared__ float4 red[256];

    float kappa = exp2_f(lk[0] * LOG2E);
    kappa = fminf(fmaxf(kappa, 0.5f), 50.0f);

    float4 psum = make_float4(0.f, 0.f, 0.f, 0.f);
    for (int d = tid; d < D; d += 256) {
        const int idx = r * D + d;
        const float thv  = th[idx];
        const float ineq = tanh_f(isp[idx]);
        const float es   = tanh_f(esp[idx]);
        const float mm   = sig_f(ml[idx]);
        const float g0 = gl[0*D + d], g1 = gl[1*D + d], g2 = gl[2*D + d], g3 = gl[3*D + d];
        const float mx = fmaxf(fmaxf(g0, g1), fmaxf(g2, g3));
        const float e0 = exp2_f((g0 - mx) * LOG2E), e1 = exp2_f((g1 - mx) * LOG2E);
        const float e2 = exp2_f((g2 - mx) * LOG2E), e3 = exp2_f((g3 - mx) * LOG2E);
        const float inv = 1.0f / (e0 + e1 + e2 + e3);
        const float a0 = e0 * inv, a1 = e1 * inv, a2 = e2 * inv, a3 = e3 * inv;

        const float fa = -kappa * ineq * LOG2E;   // exp2(fa*x+fb) == exp(-kappa*ineq*(x-th))
        const float fb = -fa * thv;
        const float s  = mm * es;
        const float s0 = s * a0, s1 = s * a1, s2 = s * a2, s3 = s * a3;

        const int chunk = d >> 1, j = d & 1;
        float* pc = ws + OFF_PB + ((size_t)r * 256 + chunk) * 12;
        pc[j]      = fb;
        pc[2 + j]  = fa;
        pc[4 + j]  = s0;
        pc[6 + j]  = s1;
        pc[8 + j]  = s2;
        pc[10 + j] = s3;
        psum.x += s0; psum.y += s1; psum.z += s2; psum.w += s3;
    }
    red[tid] = psum;
    __syncthreads();
    for (int s = 128; s > 0; s >>= 1) {
        if (tid < s) {
            red[tid].x += red[tid + s].x;
            red[tid].y += red[tid + s].y;
            red[tid].z += red[tid + s].z;
            red[tid].w += red[tid + s].w;
        }
        __syncthreads();
    }
    if (tid == 0) {
        const float4 base = red[0];
        const float gm0 = sig_f(gml[r * G + 0]);
        const float gm1 = sig_f(gml[r * G + 1]);
        const float gm2 = sig_f(gml[r * G + 2]);
        const float gm3 = sig_f(gml[r * G + 3]);
        const float en  = gm0 + gm1 + gm2 + gm3 + 1e-6f;
        const float k   = sig_f(kf[r]) * en;
        float* epi = ws + OFF_EPI + r * 12;
        epi[0] = 6.0f * (base.x + tg[r * G + 0]) * LOG2E;
        epi[1] = 6.0f * (base.y + tg[r * G + 1]) * LOG2E;
        epi[2] = 6.0f * (base.z + tg[r * G + 2]) * LOG2E;
        epi[3] = 6.0f * (base.w + tg[r * G + 3]) * LOG2E;
        epi[4] = gm0; epi[5] = gm1; epi[6] = gm2; epi[7] = gm3;
        epi[8] = 8.0f * k * LOG2E;
        epi[9] = hw[r];
        epi[10] = 0.f; epi[11] = 0.f;
    }
}

// ---------------- Kernel 2: the 134M-element hot loop ----------------
// Grid: 1024 blocks (8 btiles x 128 rblks, r fastest -> 64 consecutive blocks share
// one 64KB x-tile = L2-hot) x 512 thr = 8 waves = 2 r x 4 d-quarters. Wave: 1 r x
// 128 b (lane = b-pair) x 128 d. NO LDS staging, NO barriers in the loop.
// Everything (params broadcast + xT) rides the single IN-ORDER vmcnt queue ->
// compiler emits precise vmcnt(N) partial waits; A/B distance-1 + 8 waves/SIMD
// covers L2 latency. Live set ~50 VGPR: fits the allocator's hard 64-VGPR
// (8 waves/EU) target with slack -> no spill, no load-sinking (R5/R9/R10 lesson:
// design under the cap instead of fighting it). d-quarters merged via 12KB LDS
// at the end -> part is [R][B][4] (4 MB).
struct PB4 { float4 a, b, c; };   // one chunk's params: {fb0,fb1,fa0,fa1},{q0d0,q0d1,q1d0,q1d1},{q2d0,q2d1,q3d0,q3d1}

__global__ __launch_bounds__(512)
void sge_main(const float* __restrict__ ws, float* __restrict__ part)
{
    __shared__ float mrg[2][3][64][8];   // 12 KB: (rl, dq-1, lane, 8 acc floats)

    const int tid  = threadIdx.x;
    const int lane = tid & 63;
    const int w    = __builtin_amdgcn_readfirstlane(tid >> 6);
    const int rl   = w >> 2;              // 0..1
    const int dq   = w & 3;               // d-quarter 0..3
    const int bt   = blockIdx.x & 7;      // 0..7  (128 b each)
    const int rblk = blockIdx.x >> 3;     // 0..127 (r fastest across blocks)
    const int r    = rblk * 2 + rl;
    const int b0   = bt * 128 + 2 * lane;

    // opaque zero in a VGPR keeps the param address vector-resident -> global_load
    // (in-order vmcnt), never s_load (out-of-order SMEM poison, R3/R6/R7's 55% cap).
    int vz; asm volatile("v_mov_b32 %0, 0" : "=v"(vz));
    const float* pp = ws + OFF_PB + ((size_t)r * 256 + (size_t)dq * 64) * 12 + vz;
    const float* xp = ws + OFF_XT + (size_t)(dq * 128) * B + b0;   // per-lane address

    f2 acc0 = mk2(0.f,0.f), acc1 = mk2(0.f,0.f), acc2 = mk2(0.f,0.f), acc3 = mk2(0.f,0.f);

    auto ldP = [&](PB4& P, int ch) {
        const float4* q = reinterpret_cast<const float4*>(pp + ch * 12);
        P.a = q[0]; P.b = q[1]; P.c = q[2];
    };
    auto ldX = [&](f2& x0, f2& x1, int ch) {
        x0 = *reinterpret_cast<const f2*>(xp + (size_t)(2 * ch)     * B);
        x1 = *reinterpret_cast<const f2*>(xp + (size_t)(2 * ch + 1) * B);
    };
    auto compute = [&](const PB4& P, f2 xv0, f2 xv1) {
        const f2 t0 = __builtin_elementwise_fma(xv0, mk2(P.a.z, P.a.z), mk2(P.a.x, P.a.x));
        const f2 t1 = __builtin_elementwise_fma(xv1, mk2(P.a.w, P.a.w), mk2(P.a.y, P.a.y));
        f2 e0, e1;
        e0.x = exp2_f(t0.x); e0.y = exp2_f(t0.y);
        e1.x = exp2_f(t1.x); e1.y = exp2_f(t1.y);
        const f2 u0 = e0 + 1.0f, u1 = e1 + 1.0f;
        const float P0 = u0.x * u0.y, P1 = u1.x * u1.y;
        const float rp = rcp_f(P0 * P1);          // ONE rcp per 4 sigmoids
        const float i0 = rp * P1, i1 = rp * P0;   // 1/P0, 1/P1
        const f2 c0 = mk2(u0.y, u0.x) * mk2(i0, i0);   // sigmoid pair, d0 x {b even, b odd}
        const f2 c1 = mk2(u1.y, u1.x) * mk2(i1, i1);   // sigmoid pair, d1
        acc0 = __builtin_elementwise_fma(mk2(P.b.x, P.b.x), c0, acc0);
        acc0 = __builtin_elementwise_fma(mk2(P.b.y, P.b.y), c1, acc0);
        acc1 = __builtin_elementwise_fma(mk2(P.b.z, P.b.z), c0, acc1);
        acc1 = __builtin_elementwise_fma(mk2(P.b.w, P.b.w), c1, acc1);
        acc2 = __builtin_elementwise_fma(mk2(P.c.x, P.c.x), c0, acc2);
        acc2 = __builtin_elementwise_fma(mk2(P.c.y, P.c.y), c1, acc2);
        acc3 = __builtin_elementwise_fma(mk2(P.c.z, P.c.z), c0, acc3);
        acc3 = __builtin_elementwise_fma(mk2(P.c.w, P.c.w), c1, acc3);
    };

    PB4 PA, PBs;
    f2 xA0, xA1, xB0, xB1;
    ldP(PA, 0); ldX(xA0, xA1, 0);

    // A/B distance-1: compute(PA) waits vmcnt(5) (PB batch in flight), never a full
    // drain. 8 waves/SIMD add ~7x chunk-time of extra cover on top.
    #pragma unroll 1
    for (int c = 0; c < 64; c += 2) {
        ldP(PBs, c + 1); ldX(xB0, xB1, c + 1);
        compute(PA, xA0, xA1);
        const int cn = (c + 2 < 64) ? (c + 2) : 63;   // tail prefetch dup, harmless
        ldP(PA, cn); ldX(xA0, xA1, cn);
        compute(PBs, xB0, xB1);
    }

    // ---- merge the 4 d-quarters of each r inside the block (2 barriers total) ----
    if (dq != 0) {
        float* m = &mrg[rl][dq - 1][lane][0];
        m[0] = acc0.x; m[1] = acc0.y; m[2] = acc1.x; m[3] = acc1.y;
        m[4] = acc2.x; m[5] = acc2.y; m[6] = acc3.x; m[7] = acc3.y;
    }
    __syncthreads();
    if (dq == 0) {
        #pragma unroll
        for (int k = 0; k < 3; ++k) {
            const float* m = &mrg[rl][k][lane][0];
            acc0 += mk2(m[0], m[1]);
            acc1 += mk2(m[2], m[3]);
            acc2 += mk2(m[4], m[5]);
            acc3 += mk2(m[6], m[7]);
        }
        const float4 ve = make_float4(acc0.x, acc1.x, acc2.x, acc3.x);   // b even
        const float4 vo = make_float4(acc0.y, acc1.y, acc2.y, acc3.y);   // b odd
        float4* dst = reinterpret_cast<float4*>(part) + ((size_t)r * B + b0);
        dst[0] = ve; dst[1] = vo;
    }
}

// ---------------- Kernel 3a: nonlinear chain per (b,r), partial reduce over r ----------------
// Grid: 16 b-groups x 8 r-slices = 128 blocks x 256 thr (64 lanes=b, 4 subs x 8 r).
__global__ __launch_bounds__(256)
void sge_fin1(const float* __restrict__ part, const float* __restrict__ ws,
              float* __restrict__ zp)
{
    __shared__ float red[256];
    const int tid  = threadIdx.x;
    const int lane = tid & 63;
    const int sub  = tid >> 6;        // 0..3
    const int bg   = blockIdx.x;      // 0..15
    const int rs   = blockIdx.y;      // 0..7
    const int b    = bg * 64 + lane;
    const float C12 = -12.0f * LOG2E;
    const float C8  = -8.0f  * LOG2E;

    float s = 0.f;
    #pragma unroll 1
    for (int rr = 0; rr < 8; ++rr) {
        const int r = rs * 32 + sub * 8 + rr;
        const float4 v = reinterpret_cast<const float4*>(part)[(size_t)r * B + b];
        const float* epi = ws + OFF_EPI + r * 12;
        const float pg0 = rcp_f(1.0f + exp2_f(fmaf(C12, v.x, epi[0])));
        const float pg1 = rcp_f(1.0f + exp2_f(fmaf(C12, v.y, epi[1])));
        const float pg2 = rcp_f(1.0f + exp2_f(fmaf(C12, v.z, epi[2])));
        const float pg3 = rcp_f(1.0f + exp2_f(fmaf(C12, v.w, epi[3])));
        float score = pg0 * epi[4];
        score = fmaf(pg1, epi[5], score);
        score = fmaf(pg2, epi[6], score);
        score = fmaf(pg3, epi[7], score);
        const float z = rcp_f(1.0f + exp2_f(fmaf(C8, score, epi[8])));
        s = fmaf(epi[9], z, s);
    }
    red[tid] = s;
    __syncthreads();
    if (sub == 0)
        zp[(size_t)rs * B + b] = red[lane] + red[64 + lane] + red[128 + lane] + red[192 + lane];
}

// ---------------- Kernel 3b: final deterministic sum over r-slices ----------------
__global__ __launch_bounds__(256)
void sge_fin2(const float* __restrict__ zp, const float* __restrict__ hb,
              float* __restrict__ y)
{
    const int b = blockIdx.x * 256 + threadIdx.x;
    float s = hb[0];
    #pragma unroll
    for (int k = 0; k < 8; ++k) s += zp[(size_t)k * B + b];
    y[b] = s;
}

extern "C" void kernel_launch(void* const* d_in, const int* in_sizes, int n_in,
                              void* d_out, int out_size, void* d_ws, size_t ws_size,
                              hipStream_t stream)
{
    const float* x   = (const float*)d_in[0];
    const float* th  = (const float*)d_in[1];
    const float* isp = (const float*)d_in[2];
    const float* esp = (const float*)d_in[3];
    const float* ml  = (const float*)d_in[4];
    const float* lk  = (const float*)d_in[5];
    const float* gl  = (const float*)d_in[6];
    const float* tg  = (const float*)d_in[7];
    const float* gml = (const float*)d_in[8];
    const float* kf  = (const float*)d_in[9];
    const float* hw  = (const float*)d_in[10];
    const float* hb  = (const float*)d_in[11];
    float* ws = (float*)d_ws;
    float* y  = (float*)d_out;

    sge_transpose<<<dim3(D / 64, B / 64), 256, 0, stream>>>(x, ws + OFF_XT);
    sge_precompute<<<R, 256, 0, stream>>>(th, isp, esp, ml, lk, gl, tg, gml, kf, hw, ws);
    sge_main<<<1024, 512, 0, stream>>>(ws, ws + OFF_PART);
    sge_fin1<<<dim3(16, 8), 256, 0, stream>>>(ws + OFF_PART, ws, ws + OFF_ZP);
    sge_fin2<<<B / 256, 256, 0, stream>>>(ws + OFF_ZP, hb, y);
}